// Round 7
// baseline (31.551 us; speedup 1.0000x reference)
//
#include <hip/hip_runtime.h>

// SmartCNN round 7: round-3 structure (best, 24.3 us) + nontemporal output
// stores. Output (100.7 MB) is write-once/never-re-read; nt stores stream
// past L2/L3 write-allocate. Single-variable experiment vs round 3.
// (Round 6 failed to compile: __builtin_nontemporal_store needs a NATIVE
// vector type, not HIP_vector_type<float,4> -> use ext_vector_type(4).)

typedef float f32x4 __attribute__((ext_vector_type(4)));

__device__ __forceinline__ void nt_store4(float4 v, float4* p) {
    f32x4 nv = { v.x, v.y, v.z, v.w };
    __builtin_nontemporal_store(nv, (f32x4*)p);
}

__global__ __launch_bounds__(256) void smartcnn_kernel(
    const float* __restrict__ x,
    const float* __restrict__ W0,
    const float* __restrict__ b0,
    const float* __restrict__ W1,
    float* __restrict__ out,
    int B)
{
    // flip-specialized tables: idx = flip*44 + o*11 + e   (e = log2 class 0..10)
    __shared__ float tab0h[176], tab1h[176];  // W0 tap0 / tap1 (horizontal conv)
    __shared__ float tab0v[176], tab1v[176];  // W1 tap0 / tap1 (vertical conv)
    __shared__ float sC0[16], sC1[16];        // per (flip,o): bias + mask contribution

    const int t = threadIdx.x;
    if (t < 176) {
        int flip = t / 44, rem = t % 44, o = rem / 11, e = rem % 11;
        int fvv = flip >> 1, fhh = flip & 1;
        int ch;                              // scrambled channel for class e
        if (e == 0)      ch = fvv ? 0 : 1;   // empty (swaps with mask if fv)
        else if (e == 1) ch = fhh ? 3 : 2;   // class1/class2 swap if fh
        else if (e == 2) ch = fhh ? 2 : 3;
        else             ch = 1 + e;
        tab0h[t] = W0[o * 24 + ch * 2 + 0];
        tab1h[t] = W0[o * 24 + ch * 2 + 1];
        tab0v[t] = W1[o * 24 + ch * 2 + 0];
        tab1v[t] = W1[o * 24 + ch * 2 + 1];
    }
    if (t < 16) {
        int flip = t >> 2, o = t & 3, mcf = (flip >> 1) & 1;  // mask channel = fv?1:0
        sC0[t] = b0[o] + W0[o * 24 + mcf * 2] + W0[o * 24 + mcf * 2 + 1];
        sC1[t] =          W1[o * 24 + mcf * 2] + W1[o * 24 + mcf * 2 + 1];
    }
    __syncthreads();

    int gq = blockIdx.x * 256 + t;
    int b = gq >> 2;        // board
    int q = gq & 3;         // which float4 of each 64B output line
    if (b >= B) return;

    // load full board (quad lanes hit the same line; L1 serves the re-reads)
    const float4* x4 = (const float4*)x + (size_t)b * 4;
    float4 r0 = x4[0], r1 = x4[1], r2 = x4[2], r3 = x4[3];

    // corner argmax on the ORIGINAL board (first-max wins)
    float best = r0.x; int ix = 0;
    if (r0.w > best) { best = r0.w; ix = 1; }
    if (r3.x > best) { best = r3.x; ix = 2; }
    if (r3.w > best) { best = r3.w; ix = 3; }
    const int flipsel = ix;                 // fv*2 + fh
    const int fv = ix >> 1, fh = ix & 1;
    const int M  = fv * 12 + fh * 3;        // flipped-cell -> orig-cell XOR mask
    const int fb = flipsel * 44;            // table base (entries)

    // packed nibble classes of the ORIGINAL board, cell = row*4+col
#define EVAL(v) (max((int)(__float_as_uint(v) >> 23) - 127, 0))
    unsigned pack0 = (unsigned)EVAL(r0.x)        | ((unsigned)EVAL(r0.y) << 4)  |
                     ((unsigned)EVAL(r0.z) << 8)  | ((unsigned)EVAL(r0.w) << 12) |
                     ((unsigned)EVAL(r1.x) << 16) | ((unsigned)EVAL(r1.y) << 20) |
                     ((unsigned)EVAL(r1.z) << 24) | ((unsigned)EVAL(r1.w) << 28);
    unsigned pack1 = (unsigned)EVAL(r2.x)        | ((unsigned)EVAL(r2.y) << 4)  |
                     ((unsigned)EVAL(r2.z) << 8)  | ((unsigned)EVAL(r2.w) << 12) |
                     ((unsigned)EVAL(r3.x) << 16) | ((unsigned)EVAL(r3.y) << 20) |
                     ((unsigned)EVAL(r3.z) << 24) | ((unsigned)EVAL(r3.w) << 28);
#undef EVAL

    // class of orig cell c (0..15)
#define EX(c) (int)(((c) < 8 ? pack0 : pack1) >> (((c) & 7) * 4) & 15u)

    float4* out4 = (float4*)out + (size_t)b * 24;

#pragma unroll
    for (int rp = 0; rp < 3; ++rp) {        // rp = r%3 ; handles zh (r=rp) and zv (r=rp+3)
        const int n  = rp * 4 + q;          // f4 index within 48-float half
        const int o  = (n * 11) >> 5;       // n/3 for n<12
        const int s  = n - 3 * o;           // sub-row 0..2
        const int f1 = (s == 2) ? 1 : 0;
        const int f2 = (s >= 1) ? 1 : 0;
        const int s5 = s * 5;
        const int base = fb + o * 11;

        // ---- zh: cells (i,j),(i,j+1) in flipped space; cf = 5s+c+carry ----
        {
            const float Ch = sC0[flipsel * 4 + o];
            int c0 = s5, c1 = s5 + 1 + f1, c2 = s5 + 2 + f2, c3 = s5 + 4;
            float4 val;
            val.x = fmaxf(Ch + tab0h[base + EX(c0 ^ M)] + tab1h[base + EX((c0 + 1) ^ M)], 0.f);
            val.y = fmaxf(Ch + tab0h[base + EX(c1 ^ M)] + tab1h[base + EX((c1 + 1) ^ M)], 0.f);
            val.z = fmaxf(Ch + tab0h[base + EX(c2 ^ M)] + tab1h[base + EX((c2 + 1) ^ M)], 0.f);
            val.w = fmaxf(Ch + tab0h[base + EX(c3 ^ M)] + tab1h[base + EX((c3 + 1) ^ M)], 0.f);
            nt_store4(val, &out4[rp * 4 + q]);
        }
        // ---- zv^T: cells (qq,a),(qq+1,a); cf = 5s+4c-11*carry ----
        {
            const float Cv = sC1[flipsel * 4 + o];
            int c0 = s5, c1 = s5 + 4 - 11 * f1, c2 = s5 + 8 - 11 * f2, c3 = s5 + 1;
            float4 val;
            val.x = fmaxf(Cv + tab0v[base + EX(c0 ^ M)] + tab1v[base + EX((c0 + 4) ^ M)], 0.f);
            val.y = fmaxf(Cv + tab0v[base + EX(c1 ^ M)] + tab1v[base + EX((c1 + 4) ^ M)], 0.f);
            val.z = fmaxf(Cv + tab0v[base + EX(c2 ^ M)] + tab1v[base + EX((c2 + 4) ^ M)], 0.f);
            val.w = fmaxf(Cv + tab0v[base + EX(c3 ^ M)] + tab1v[base + EX((c3 + 4) ^ M)], 0.f);
            nt_store4(val, &out4[12 + rp * 4 + q]);
        }
    }
#undef EX
}

extern "C" void kernel_launch(void* const* d_in, const int* in_sizes, int n_in,
                              void* d_out, int out_size, void* d_ws, size_t ws_size,
                              hipStream_t stream) {
    const float* x  = (const float*)d_in[0];
    const float* W0 = (const float*)d_in[1];
    const float* b0 = (const float*)d_in[2];
    const float* W1 = (const float*)d_in[3];
    float* out = (float*)d_out;

    int B = in_sizes[0] / 16;                 // boards
    int total = B * 4;                        // 4 lanes per board
    int blocks = (total + 255) / 256;
    smartcnn_kernel<<<blocks, 256, 0, stream>>>(x, W0, b0, W1, out, B);
}

// Round 8
// 26.429 us; speedup vs baseline: 1.1938x; 1.1938x over previous
//
#include <hip/hip_runtime.h>

// SmartCNN round 8: R3 structure + 4-task unroll with depth-1 prefetch.
//  - 1024 blocks x 256 threads; each thread processes 4 board-quads strided
//    by gridDim*64 boards -> single dispatch pass (4 blocks/CU), ramp /16,
//    table init amortized 4x.
//  - next task's board load is issued BEFORE current task's compute/stores
//    -> HBM read latency hides under table gathers + stores.
//  - store mapping unchanged from R3 (best): quad lane q of board b writes
//    float4s 4r+q -> every wave store = 16 full 64B lines.
//  - normal (cached) stores: R7 proved nt stores regress (24.3 -> 31.6).

__global__ __launch_bounds__(256) void smartcnn_kernel(
    const float* __restrict__ x,
    const float* __restrict__ W0,
    const float* __restrict__ b0,
    const float* __restrict__ W1,
    float* __restrict__ out,
    int B)
{
    // flip-specialized tables: idx = flip*44 + o*11 + e   (e = log2 class 0..10)
    __shared__ float tab0h[176], tab1h[176];  // W0 tap0 / tap1 (horizontal conv)
    __shared__ float tab0v[176], tab1v[176];  // W1 tap0 / tap1 (vertical conv)
    __shared__ float sC0[16], sC1[16];        // per (flip,o): bias + mask contrib

    const int t = threadIdx.x;
    if (t < 176) {
        int flip = t / 44, rem = t % 44, o = rem / 11, e = rem % 11;
        int fvv = flip >> 1, fhh = flip & 1;
        int ch;                              // scrambled channel for class e
        if (e == 0)      ch = fvv ? 0 : 1;   // empty (swaps with mask if fv)
        else if (e == 1) ch = fhh ? 3 : 2;   // class1/class2 swap if fh
        else if (e == 2) ch = fhh ? 2 : 3;
        else             ch = 1 + e;
        tab0h[t] = W0[o * 24 + ch * 2 + 0];
        tab1h[t] = W0[o * 24 + ch * 2 + 1];
        tab0v[t] = W1[o * 24 + ch * 2 + 0];
        tab1v[t] = W1[o * 24 + ch * 2 + 1];
    }
    if (t < 16) {
        int flip = t >> 2, o = t & 3, mcf = (flip >> 1) & 1;
        sC0[t] = b0[o] + W0[o * 24 + mcf * 2] + W0[o * 24 + mcf * 2 + 1];
        sC1[t] =          W1[o * 24 + mcf * 2] + W1[o * 24 + mcf * 2 + 1];
    }
    __syncthreads();

    const int tid = blockIdx.x * 256 + t;
    const int q = tid & 3;                     // task-invariant output column
    const int bstride = (gridDim.x * 256) >> 2;

    int bn = tid >> 2;                         // first board
    // prefetch first board
    float4 n0, n1, n2, n3;
    if (bn < B) {
        const float4* xp = (const float4*)x + (size_t)bn * 4;
        n0 = xp[0]; n1 = xp[1]; n2 = xp[2]; n3 = xp[3];
    }

#pragma unroll
    for (int k = 0; k < 4; ++k) {
        const int b = bn;
        float4 r0 = n0, r1 = n1, r2 = n2, r3 = n3;
        bn += bstride;
        if (k < 3 && bn < B) {                 // issue next load before compute
            const float4* xp = (const float4*)x + (size_t)bn * 4;
            n0 = xp[0]; n1 = xp[1]; n2 = xp[2]; n3 = xp[3];
        }
        if (b >= B) continue;

        // corner argmax on the ORIGINAL board (first-max wins)
        float best = r0.x; int ix = 0;
        if (r0.w > best) { best = r0.w; ix = 1; }
        if (r3.x > best) { best = r3.x; ix = 2; }
        if (r3.w > best) { best = r3.w; ix = 3; }
        const int flipsel = ix;                // fv*2 + fh
        const int fv = ix >> 1, fh = ix & 1;
        const int M  = fv * 12 + fh * 3;       // flipped-cell -> orig-cell XOR
        const int fb = flipsel * 44;

        // packed nibble classes of the ORIGINAL board, cell = row*4+col
#define EVAL(v) (max((int)(__float_as_uint(v) >> 23) - 127, 0))
        unsigned pack0 = (unsigned)EVAL(r0.x)        | ((unsigned)EVAL(r0.y) << 4)  |
                         ((unsigned)EVAL(r0.z) << 8)  | ((unsigned)EVAL(r0.w) << 12) |
                         ((unsigned)EVAL(r1.x) << 16) | ((unsigned)EVAL(r1.y) << 20) |
                         ((unsigned)EVAL(r1.z) << 24) | ((unsigned)EVAL(r1.w) << 28);
        unsigned pack1 = (unsigned)EVAL(r2.x)        | ((unsigned)EVAL(r2.y) << 4)  |
                         ((unsigned)EVAL(r2.z) << 8)  | ((unsigned)EVAL(r2.w) << 12) |
                         ((unsigned)EVAL(r3.x) << 16) | ((unsigned)EVAL(r3.y) << 20) |
                         ((unsigned)EVAL(r3.z) << 24) | ((unsigned)EVAL(r3.w) << 28);
#undef EVAL

#define EX(c) (int)(((c) < 8 ? pack0 : pack1) >> (((c) & 7) * 4) & 15u)

        float4* out4 = (float4*)out + (size_t)b * 24;

#pragma unroll
        for (int rp = 0; rp < 3; ++rp) {
            const int n  = rp * 4 + q;         // f4 index within 48-float half
            const int o  = (n * 11) >> 5;      // n/3 for n<12
            const int s  = n - 3 * o;          // sub-row 0..2
            const int f1 = (s == 2) ? 1 : 0;
            const int f2 = (s >= 1) ? 1 : 0;
            const int s5 = s * 5;
            const int base = fb + o * 11;

            // zh: cells (i,j),(i,j+1) in flipped space
            {
                const float Ch = sC0[flipsel * 4 + o];
                int c0 = s5, c1 = s5 + 1 + f1, c2 = s5 + 2 + f2, c3 = s5 + 4;
                float4 val;
                val.x = fmaxf(Ch + tab0h[base + EX(c0 ^ M)] + tab1h[base + EX((c0 + 1) ^ M)], 0.f);
                val.y = fmaxf(Ch + tab0h[base + EX(c1 ^ M)] + tab1h[base + EX((c1 + 1) ^ M)], 0.f);
                val.z = fmaxf(Ch + tab0h[base + EX(c2 ^ M)] + tab1h[base + EX((c2 + 1) ^ M)], 0.f);
                val.w = fmaxf(Ch + tab0h[base + EX(c3 ^ M)] + tab1h[base + EX((c3 + 1) ^ M)], 0.f);
                out4[rp * 4 + q] = val;
            }
            // zv^T: cells (qq,a),(qq+1,a)
            {
                const float Cv = sC1[flipsel * 4 + o];
                int c0 = s5, c1 = s5 + 4 - 11 * f1, c2 = s5 + 8 - 11 * f2, c3 = s5 + 1;
                float4 val;
                val.x = fmaxf(Cv + tab0v[base + EX(c0 ^ M)] + tab1v[base + EX((c0 + 4) ^ M)], 0.f);
                val.y = fmaxf(Cv + tab0v[base + EX(c1 ^ M)] + tab1v[base + EX((c1 + 4) ^ M)], 0.f);
                val.z = fmaxf(Cv + tab0v[base + EX(c2 ^ M)] + tab1v[base + EX((c2 + 4) ^ M)], 0.f);
                val.w = fmaxf(Cv + tab0v[base + EX(c3 ^ M)] + tab1v[base + EX((c3 + 4) ^ M)], 0.f);
                out4[12 + rp * 4 + q] = val;
            }
        }
#undef EX
    }
}

extern "C" void kernel_launch(void* const* d_in, const int* in_sizes, int n_in,
                              void* d_out, int out_size, void* d_ws, size_t ws_size,
                              hipStream_t stream) {
    const float* x  = (const float*)d_in[0];
    const float* W0 = (const float*)d_in[1];
    const float* b0 = (const float*)d_in[2];
    const float* W1 = (const float*)d_in[3];
    float* out = (float*)d_out;

    int B = in_sizes[0] / 16;                  // boards
    // 4 tasks per thread: threads = B*4/4 = B; blocks = B/256
    int blocks = (B + 255) / 256;
    smartcnn_kernel<<<blocks, 256, 0, stream>>>(x, W0, b0, W1, out, B);
}

// Round 9
// 24.252 us; speedup vs baseline: 1.3010x; 1.0898x over previous
//
#include <hip/hip_runtime.h>

// SmartCNN round 9: EXACT round-3 kernel (best, 24.3 us) + __launch_bounds__
// (256, 8): force VGPR <= 64 so 8 waves/SIMD (32/CU) become resident,
// doubling latency-hiding for the load->gather->store chain. Single-variable
// occupancy probe.
//
// Mapping: lane quad q=0..3 of board b writes float4s m = 4r+q (r=0..5) at
// out4[b*24+m] -> every store instr = 16 full 64B lines. Flip scramble is
// folded into 4 flip-specialized weight tables in LDS; spatial flip into a
// cell-index XOR (fv:^12, fh:^3); per-cell classes into two packed nibble
// u32s (runtime cell index = bit-extract, never a register-array index).

__global__ __launch_bounds__(256, 8) void smartcnn_kernel(
    const float* __restrict__ x,
    const float* __restrict__ W0,
    const float* __restrict__ b0,
    const float* __restrict__ W1,
    float* __restrict__ out,
    int B)
{
    // flip-specialized tables: idx = flip*44 + o*11 + e   (e = log2 class 0..10)
    __shared__ float tab0h[176], tab1h[176];  // W0 tap0 / tap1 (horizontal conv)
    __shared__ float tab0v[176], tab1v[176];  // W1 tap0 / tap1 (vertical conv)
    __shared__ float sC0[16], sC1[16];        // per (flip,o): bias + mask contribution

    const int t = threadIdx.x;
    if (t < 176) {
        int flip = t / 44, rem = t % 44, o = rem / 11, e = rem % 11;
        int fvv = flip >> 1, fhh = flip & 1;
        int ch;                              // scrambled channel for class e
        if (e == 0)      ch = fvv ? 0 : 1;   // empty (swaps with mask if fv)
        else if (e == 1) ch = fhh ? 3 : 2;   // class1/class2 swap if fh
        else if (e == 2) ch = fhh ? 2 : 3;
        else             ch = 1 + e;
        tab0h[t] = W0[o * 24 + ch * 2 + 0];
        tab1h[t] = W0[o * 24 + ch * 2 + 1];
        tab0v[t] = W1[o * 24 + ch * 2 + 0];
        tab1v[t] = W1[o * 24 + ch * 2 + 1];
    }
    if (t < 16) {
        int flip = t >> 2, o = t & 3, mcf = (flip >> 1) & 1;  // mask channel = fv?1:0
        sC0[t] = b0[o] + W0[o * 24 + mcf * 2] + W0[o * 24 + mcf * 2 + 1];
        sC1[t] =          W1[o * 24 + mcf * 2] + W1[o * 24 + mcf * 2 + 1];
    }
    __syncthreads();

    int gq = blockIdx.x * 256 + t;
    int b = gq >> 2;        // board
    int q = gq & 3;         // which float4 of each 64B output line
    if (b >= B) return;

    // load full board (quad lanes hit the same line; L1 serves the re-reads)
    const float4* x4 = (const float4*)x + (size_t)b * 4;
    float4 r0 = x4[0], r1 = x4[1], r2 = x4[2], r3 = x4[3];

    // corner argmax on the ORIGINAL board (first-max wins)
    float best = r0.x; int ix = 0;
    if (r0.w > best) { best = r0.w; ix = 1; }
    if (r3.x > best) { best = r3.x; ix = 2; }
    if (r3.w > best) { best = r3.w; ix = 3; }
    const int flipsel = ix;                 // fv*2 + fh
    const int fv = ix >> 1, fh = ix & 1;
    const int M  = fv * 12 + fh * 3;        // flipped-cell -> orig-cell XOR mask
    const int fb = flipsel * 44;            // table base (entries)

    // packed nibble classes of the ORIGINAL board, cell = row*4+col
#define EVAL(v) (max((int)(__float_as_uint(v) >> 23) - 127, 0))
    unsigned pack0 = (unsigned)EVAL(r0.x)        | ((unsigned)EVAL(r0.y) << 4)  |
                     ((unsigned)EVAL(r0.z) << 8)  | ((unsigned)EVAL(r0.w) << 12) |
                     ((unsigned)EVAL(r1.x) << 16) | ((unsigned)EVAL(r1.y) << 20) |
                     ((unsigned)EVAL(r1.z) << 24) | ((unsigned)EVAL(r1.w) << 28);
    unsigned pack1 = (unsigned)EVAL(r2.x)        | ((unsigned)EVAL(r2.y) << 4)  |
                     ((unsigned)EVAL(r2.z) << 8)  | ((unsigned)EVAL(r2.w) << 12) |
                     ((unsigned)EVAL(r3.x) << 16) | ((unsigned)EVAL(r3.y) << 20) |
                     ((unsigned)EVAL(r3.z) << 24) | ((unsigned)EVAL(r3.w) << 28);
#undef EVAL

    // class of orig cell c (0..15)
#define EX(c) (int)(((c) < 8 ? pack0 : pack1) >> (((c) & 7) * 4) & 15u)

    float4* out4 = (float4*)out + (size_t)b * 24;

#pragma unroll
    for (int rp = 0; rp < 3; ++rp) {        // rp = r%3 ; handles zh (r=rp) and zv (r=rp+3)
        const int n  = rp * 4 + q;          // f4 index within 48-float half
        const int o  = (n * 11) >> 5;       // n/3 for n<12
        const int s  = n - 3 * o;           // sub-row 0..2
        const int f1 = (s == 2) ? 1 : 0;
        const int f2 = (s >= 1) ? 1 : 0;
        const int s5 = s * 5;
        const int base = fb + o * 11;

        // ---- zh: cells (i,j),(i,j+1) in flipped space; cf = 5s+c+carry ----
        {
            const float Ch = sC0[flipsel * 4 + o];
            int c0 = s5, c1 = s5 + 1 + f1, c2 = s5 + 2 + f2, c3 = s5 + 4;
            float4 val;
            val.x = fmaxf(Ch + tab0h[base + EX(c0 ^ M)] + tab1h[base + EX((c0 + 1) ^ M)], 0.f);
            val.y = fmaxf(Ch + tab0h[base + EX(c1 ^ M)] + tab1h[base + EX((c1 + 1) ^ M)], 0.f);
            val.z = fmaxf(Ch + tab0h[base + EX(c2 ^ M)] + tab1h[base + EX((c2 + 1) ^ M)], 0.f);
            val.w = fmaxf(Ch + tab0h[base + EX(c3 ^ M)] + tab1h[base + EX((c3 + 1) ^ M)], 0.f);
            out4[rp * 4 + q] = val;
        }
        // ---- zv^T: cells (qq,a),(qq+1,a); cf = 5s+4c-11*carry ----
        {
            const float Cv = sC1[flipsel * 4 + o];
            int c0 = s5, c1 = s5 + 4 - 11 * f1, c2 = s5 + 8 - 11 * f2, c3 = s5 + 1;
            float4 val;
            val.x = fmaxf(Cv + tab0v[base + EX(c0 ^ M)] + tab1v[base + EX((c0 + 4) ^ M)], 0.f);
            val.y = fmaxf(Cv + tab0v[base + EX(c1 ^ M)] + tab1v[base + EX((c1 + 4) ^ M)], 0.f);
            val.z = fmaxf(Cv + tab0v[base + EX(c2 ^ M)] + tab1v[base + EX((c2 + 4) ^ M)], 0.f);
            val.w = fmaxf(Cv + tab0v[base + EX(c3 ^ M)] + tab1v[base + EX((c3 + 4) ^ M)], 0.f);
            out4[12 + rp * 4 + q] = val;
        }
    }
#undef EX
}

extern "C" void kernel_launch(void* const* d_in, const int* in_sizes, int n_in,
                              void* d_out, int out_size, void* d_ws, size_t ws_size,
                              hipStream_t stream) {
    const float* x  = (const float*)d_in[0];
    const float* W0 = (const float*)d_in[1];
    const float* b0 = (const float*)d_in[2];
    const float* W1 = (const float*)d_in[3];
    float* out = (float*)d_out;

    int B = in_sizes[0] / 16;                 // boards
    int total = B * 4;                        // 4 lanes per board
    int blocks = (total + 255) / 256;
    smartcnn_kernel<<<blocks, 256, 0, stream>>>(x, W0, b0, W1, out, B);
}